// Round 7
// baseline (85.161 us; speedup 1.0000x reference)
//
#include <hip/hip_runtime.h>
#include <hip/hip_bf16.h>
#include <stdint.h>

#define N 8192
#define K 64

typedef __attribute__((ext_vector_type(8))) __bf16 bf16x8;
typedef __attribute__((ext_vector_type(4))) float f32x4;
typedef __attribute__((address_space(3))) uint8_t lds_u8;
typedef __attribute__((address_space(1))) const uint8_t glob_u8;

// ws layout:
//   [0, 1MB)               : W0 = F_ll as bf16 (ushort), 8192*64
//   [1MB, 1MB+16KB)        : P1 term1 per-block partials (4096 f32)
//   [1MB+64KB, +4MB)       : P2 term2 per-block partial G (256 * 4096 f32)
//   [0x510000, +256B)      : R1 stage2 partials (64 f32)
//   [0x510400, +256B)      : R2 stage2 partials (64 f32)
//   [0x510800, +4B)        : cnt (last-block counter)

static __device__ __forceinline__ uint32_t f2bf(float f) {
  uint32_t x = __float_as_uint(f);
  return (x + 0x7FFFu + ((x >> 16) & 1u)) >> 16;  // RNE f32->bf16
}

// term2 + bf16 convert fused. 256 blocks, each owns 32 rows (R5 form, proven).
__global__ __launch_bounds__(256) void term2_kernel(const float* __restrict__ Fll,
                                                    const float* __restrict__ Ful,
                                                    float* __restrict__ P2,
                                                    ushort* __restrict__ W0,
                                                    unsigned* __restrict__ cnt) {
  __shared__ float sll[32][64];
  __shared__ float sul[32][64];
  const int t = threadIdx.x;
  const int j = t & 63, kq = t >> 6;  // kq uniform per wave -> broadcast LDS reads
  const size_t r0 = (size_t)blockIdx.x * 32;

  if (blockIdx.x == 0 && t == 0) *cnt = 0u;  // reset last-block counter every launch

  for (int i = t; i < 512; i += 256) {  // 32*64 f32 = 512 float4 per matrix
    ((float4*)sll)[i] = ((const float4*)(Fll + r0 * K))[i];
    ((float4*)sul)[i] = ((const float4*)(Ful + r0 * K))[i];
  }
  __syncthreads();

  // emit bf16 copy of this block's F_ll rows (flat layout matches global)
  const float* sf = (const float*)sll;
  {
    int f = t * 8;
    uint32_t r[8];
#pragma unroll
    for (int e = 0; e < 8; ++e) r[e] = f2bf(sf[f + e]);
    uint4 o;
    o.x = r[0] | (r[1] << 16);
    o.y = r[2] | (r[3] << 16);
    o.z = r[4] | (r[5] << 16);
    o.w = r[6] | (r[7] << 16);
    *(uint4*)&W0[r0 * K + f] = o;
  }

  float acc[16];
#pragma unroll
  for (int m = 0; m < 16; ++m) acc[m] = 0.f;
  for (int r = 0; r < 32; ++r) {
    float fl = sll[r][j];
#pragma unroll
    for (int m = 0; m < 16; ++m) acc[m] += sul[r][kq * 16 + m] * fl;
  }
#pragma unroll
  for (int m = 0; m < 16; ++m)
    P2[(size_t)blockIdx.x * 4096 + (kq * 16 + m) * 64 + j] = acc[m];
}

// term1: EXACT R2 structure (best measured) + two targeted edits:
//  1) grid order swapped to bi-INNER: 128 consecutive blocks share the same
//     32 KB b-panel of W0 -> it stays L2-hot instead of being re-fetched from
//     HBM under the Theta stream (the suspected ~130 MB over-fetch).
//  2) dot accumulator split 4-way (per jf) to break the serial FMA chain.
__global__ __launch_bounds__(256) void term1_kernel(const float* __restrict__ Theta,
                                                    const ushort* __restrict__ Fb,
                                                    float* __restrict__ P1) {
  __shared__ float lds[2][16 * 260];
  const int t = threadIdx.x;
  const int lane = t & 63, wave = t >> 6;
  const int bi = blockIdx.x & 127;  // INNER: consecutive blocks share bj
  const int bj = blockIdx.x >> 7;   // 32 j-tiles
  const int i0 = bi * 64;
  const int jc0 = bj * 256;
  const int l15 = lane & 15, lg = lane >> 4;

  // stage strip s: wave w loads strip-rows {w, w+4, w+8, w+12}, 1KB each.
#define STAGE(s, buf)                                                                \
  {                                                                                  \
    _Pragma("unroll") for (int q = 0; q < 4; ++q) {                                  \
      int row = wave + 4 * q;                                                        \
      const float* g = Theta + (size_t)(i0 + (s)*16 + row) * N + jc0 + lane * 4;     \
      float* l = &lds[buf][row * 260];                                               \
      __builtin_amdgcn_global_load_lds((glob_u8*)g, (lds_u8*)l, 16, 0, 0);           \
    }                                                                                \
  }

  STAGE(0, 0);

  bf16x8 afrag[4][2], bfrag[4][2];
#pragma unroll
  for (int m = 0; m < 4; ++m)
#pragma unroll
    for (int ks = 0; ks < 2; ++ks)
      afrag[m][ks] = *(const bf16x8*)&Fb[(size_t)(i0 + m * 16 + l15) * K + ks * 32 + lg * 8];
#pragma unroll
  for (int n = 0; n < 4; ++n)
#pragma unroll
    for (int ks = 0; ks < 2; ++ks)
      bfrag[n][ks] =
          *(const bf16x8*)&Fb[(size_t)(jc0 + wave * 64 + n * 16 + l15) * K + ks * 32 + lg * 8];

  float pacc[4] = {0.f, 0.f, 0.f, 0.f};
  __syncthreads();
#pragma unroll
  for (int s = 0; s < 4; ++s) {
    if (s < 3) STAGE(s + 1, (s + 1) & 1);
    f32x4 zero = {0.f, 0.f, 0.f, 0.f};
    f32x4 acc[4] = {zero, zero, zero, zero};
#pragma unroll
    for (int jf = 0; jf < 4; ++jf)
#pragma unroll
      for (int ks = 0; ks < 2; ++ks)
        acc[jf] = __builtin_amdgcn_mfma_f32_16x16x32_bf16(afrag[s][ks], bfrag[jf][ks],
                                                          acc[jf], 0, 0, 0);
    const float* cur = &lds[s & 1][0];
#pragma unroll
    for (int jf = 0; jf < 4; ++jf)
#pragma unroll
      for (int r = 0; r < 4; ++r)
        pacc[jf] += acc[jf][r] * cur[(lg * 4 + r) * 260 + wave * 64 + jf * 16 + l15];
    __syncthreads();
  }

  float p = (pacc[0] + pacc[1]) + (pacc[2] + pacc[3]);
#pragma unroll
  for (int off = 32; off > 0; off >>= 1) p += __shfl_down(p, off, 64);
  __shared__ float red[4];
  if (lane == 0) red[wave] = p;
  __syncthreads();
  if (t == 0) P1[blockIdx.x] = (red[0] + red[1]) + (red[2] + red[3]);
}

// stage2 + final merged (last-block pattern, proven). 64 blocks; block b sums
// P1 slice [b*64,+64) and finishes G cols kj in [b*64,+64) over 256 partials.
__global__ __launch_bounds__(256) void stage2_kernel(const float* __restrict__ P1,
                                                     const float* __restrict__ P2,
                                                     const float* __restrict__ lam,
                                                     float* __restrict__ out,
                                                     float* __restrict__ R1,
                                                     float* __restrict__ R2,
                                                     unsigned* __restrict__ cnt) {
  __shared__ float sg[4][64];
  __shared__ unsigned is_last;
  const int t = threadIdx.x, b = blockIdx.x;
  const int l = t & 63, q = t >> 6;
  const int kj = b * 64 + l;
  float gp = 0.f;
  for (int blk = q * 64; blk < q * 64 + 64; ++blk) gp += P2[(size_t)blk * 4096 + kj];
  sg[q][l] = gp;
  float a = (t < 64) ? P1[b * 64 + t] : 0.f;
  __syncthreads();
  if (q == 0) {
    float g = (sg[0][l] + sg[1][l]) + (sg[2][l] + sg[3][l]);
    float r2 = g * g;
    float r1 = a;
#pragma unroll
    for (int off = 32; off > 0; off >>= 1) {
      r2 += __shfl_down(r2, off, 64);
      r1 += __shfl_down(r1, off, 64);
    }
    if (l == 0) {
      R1[b] = r1;
      R2[b] = r2;
    }
  }
  if (t == 0) {
    __threadfence();  // publish R1[b]/R2[b]
    unsigned old = atomicAdd(cnt, 1u);
    __threadfence();  // acquire for last block's reads
    is_last = (old == 63u) ? 1u : 0u;
  }
  __syncthreads();
  if (is_last && t < 64) {
    float r1 = R1[t], r2 = R2[t];
#pragma unroll
    for (int off = 32; off > 0; off >>= 1) {
      r1 += __shfl_down(r1, off, 64);
      r2 += __shfl_down(r2, off, 64);
    }
    if (t == 0) out[0] = r1 + lam[0] * r2;
  }
}

extern "C" void kernel_launch(void* const* d_in, const int* in_sizes, int n_in,
                              void* d_out, int out_size, void* d_ws, size_t ws_size,
                              hipStream_t stream) {
  const float* Fll = (const float*)d_in[0];
  const float* Ful = (const float*)d_in[1];
  const float* Theta = (const float*)d_in[2];
  const float* lam = (const float*)d_in[3];
  float* out = (float*)d_out;

  char* ws = (char*)d_ws;
  ushort* W0 = (ushort*)ws;                            // 1 MB bf16 F_ll
  float* P1 = (float*)(ws + (1u << 20));               // 16 KB
  float* P2 = (float*)(ws + (1u << 20) + (1u << 16));  // 4 MB
  float* R1 = (float*)(ws + 0x510000u);
  float* R2 = (float*)(ws + 0x510400u);
  unsigned* cnt = (unsigned*)(ws + 0x510800u);

  term2_kernel<<<256, 256, 0, stream>>>(Fll, Ful, P2, W0, cnt);
  term1_kernel<<<4096, 256, 0, stream>>>(Theta, W0, P1);
  stage2_kernel<<<64, 256, 0, stream>>>(P1, P2, lam, out, R1, R2, cnt);
}

// Round 8
// 68.341 us; speedup vs baseline: 1.2461x; 1.2461x over previous
//
#include <hip/hip_runtime.h>
#include <hip/hip_bf16.h>
#include <stdint.h>

#define N 8192
#define K 64

typedef __attribute__((ext_vector_type(8))) __bf16 bf16x8;
typedef __attribute__((ext_vector_type(4))) float f32x4;
typedef __attribute__((address_space(3))) uint8_t lds_u8;
typedef __attribute__((address_space(1))) const uint8_t glob_u8;

// ws layout:
//   [0, 1MB)               : W0 = F_ll as bf16 (ushort), 8192*64
//   [1MB, 1MB+4KB)         : P1 term1 per-block partials (1024 f32)
//   [1MB+64KB, +2MB)       : P2 term2 per-block partial G (128 * 4096 f32)
//   [0x310000, +256B)      : R1 stage2 partials (64 f32)
//   [0x310400, +256B)      : R2 stage2 partials (64 f32)
//   [0x310800, +4B)        : cnt (last-block counter)

static __device__ __forceinline__ uint32_t f2bf(float f) {
  uint32_t x = __float_as_uint(f);
  return (x + 0x7FFFu + ((x >> 16) & 1u)) >> 16;  // RNE f32->bf16
}

// term2 + bf16 convert fused (R2-exact, proven). 128 blocks, each owns 64 rows.
__global__ __launch_bounds__(256) void term2_kernel(const float* __restrict__ Fll,
                                                    const float* __restrict__ Ful,
                                                    float* __restrict__ P2,
                                                    ushort* __restrict__ W0,
                                                    unsigned* __restrict__ cnt) {
  __shared__ float sll[64][64];
  __shared__ float sul[64][64];
  const int t = threadIdx.x;
  const int j = t & 63, kq = t >> 6;  // kq uniform per wave -> broadcast LDS reads
  const size_t r0 = (size_t)blockIdx.x * 64;

  if (blockIdx.x == 0 && t == 0) *cnt = 0u;  // reset last-block counter every launch

  for (int i = t; i < 1024; i += 256) {
    ((float4*)sll)[i] = ((const float4*)(Fll + r0 * K))[i];
    ((float4*)sul)[i] = ((const float4*)(Ful + r0 * K))[i];
  }
  __syncthreads();

  const float* sf = (const float*)sll;
#pragma unroll
  for (int h = 0; h < 2; ++h) {
    int f = t * 8 + h * 2048;
    uint32_t r[8];
#pragma unroll
    for (int e = 0; e < 8; ++e) r[e] = f2bf(sf[f + e]);
    uint4 o;
    o.x = r[0] | (r[1] << 16);
    o.y = r[2] | (r[3] << 16);
    o.z = r[4] | (r[5] << 16);
    o.w = r[6] | (r[7] << 16);
    *(uint4*)&W0[r0 * K + f] = o;
  }

  float acc[16];
#pragma unroll
  for (int m = 0; m < 16; ++m) acc[m] = 0.f;
  for (int r = 0; r < 64; ++r) {
    float fl = sll[r][j];
#pragma unroll
    for (int m = 0; m < 16; ++m) acc[m] += sul[r][kq * 16 + m] * fl;
  }
#pragma unroll
  for (int m = 0; m < 16; ++m)
    P2[(size_t)blockIdx.x * 4096 + (kq * 16 + m) * 64 + j] = acc[m];
}

// term1: R2 pipeline (simple __syncthreads double-buffer, bj-INNER grid order,
// sequential Theta sweep) with a 256x256 tile per block (was 64x256):
// 16 strips of 16 rows. bfrag register-resident (loaded once); afrag loaded
// just-in-time per strip (8 KB/strip, shared by the 32-block bi-group -> L2 hot).
// Cuts W0 fragment traffic per Theta byte 0.625 -> 0.25.
__global__ __launch_bounds__(256) void term1_kernel(const float* __restrict__ Theta,
                                                    const ushort* __restrict__ Fb,
                                                    float* __restrict__ P1) {
  __shared__ float lds[2][16 * 260];
  const int t = threadIdx.x;
  const int lane = t & 63, wave = t >> 6;
  const int bi = blockIdx.x >> 5;  // 32 i-tiles of 256 (OUTER)
  const int bj = blockIdx.x & 31;  // 32 j-tiles of 256 (INNER: sequential Theta)
  const int i0 = bi * 256;
  const int jc0 = bj * 256;
  const int l15 = lane & 15, lg = lane >> 4;

  // stage strip s (16 rows x 256 cols): wave w loads rows {w, w+4, w+8, w+12}.
#define STAGE(s, buf)                                                                \
  {                                                                                  \
    _Pragma("unroll") for (int q = 0; q < 4; ++q) {                                  \
      int row = wave + 4 * q;                                                        \
      const float* g = Theta + (size_t)(i0 + (s)*16 + row) * N + jc0 + lane * 4;     \
      float* l = &(buf)[row * 260];                                                  \
      __builtin_amdgcn_global_load_lds((glob_u8*)g, (lds_u8*)l, 16, 0, 0);           \
    }                                                                                \
  }

  float* cur = &lds[0][0];
  float* nxt = &lds[1][0];

  STAGE(0, cur);

  // bfrag: this wave's 64 j-cols, register-resident for all 16 strips.
  bf16x8 bfrag[4][2];
#pragma unroll
  for (int n = 0; n < 4; ++n)
#pragma unroll
    for (int ks = 0; ks < 2; ++ks)
      bfrag[n][ks] =
          *(const bf16x8*)&Fb[(size_t)(jc0 + wave * 64 + n * 16 + l15) * K + ks * 32 + lg * 8];

  // afrag for strip 0
  bf16x8 afA0, afA1;
  {
    const ushort* ar = &Fb[(size_t)(i0 + l15) * K + lg * 8];
    afA0 = *(const bf16x8*)ar;
    afA1 = *(const bf16x8*)(ar + 32);
  }

  float p = 0.f;
  __syncthreads();
  for (int s = 0; s < 16; ++s) {
    bf16x8 afN0 = afA0, afN1 = afA1;
    if (s < 15) {
      STAGE(s + 1, nxt);
      const ushort* ar = &Fb[(size_t)(i0 + (s + 1) * 16 + l15) * K + lg * 8];
      afN0 = *(const bf16x8*)ar;
      afN1 = *(const bf16x8*)(ar + 32);
    }
    f32x4 zero = {0.f, 0.f, 0.f, 0.f};
    f32x4 acc[4] = {zero, zero, zero, zero};
#pragma unroll
    for (int jf = 0; jf < 4; ++jf) {
      acc[jf] = __builtin_amdgcn_mfma_f32_16x16x32_bf16(afA0, bfrag[jf][0], acc[jf], 0, 0, 0);
      acc[jf] = __builtin_amdgcn_mfma_f32_16x16x32_bf16(afA1, bfrag[jf][1], acc[jf], 0, 0, 0);
    }
#pragma unroll
    for (int jf = 0; jf < 4; ++jf)
#pragma unroll
      for (int r = 0; r < 4; ++r)
        p += acc[jf][r] * cur[(lg * 4 + r) * 260 + wave * 64 + jf * 16 + l15];
    __syncthreads();
    { float* tmp = cur; cur = nxt; nxt = tmp; }
    afA0 = afN0;
    afA1 = afN1;
  }

#pragma unroll
  for (int off = 32; off > 0; off >>= 1) p += __shfl_down(p, off, 64);
  __shared__ float red[4];
  if (lane == 0) red[wave] = p;
  __syncthreads();
  if (t == 0) P1[blockIdx.x] = (red[0] + red[1]) + (red[2] + red[3]);
}

// stage2 + final merged (last-block pattern, proven). 64 blocks; block b sums
// P1 slice [b*16,+16) and finishes G cols kj in [b*64,+64) over 128 partials.
__global__ __launch_bounds__(256) void stage2_kernel(const float* __restrict__ P1,
                                                     const float* __restrict__ P2,
                                                     const float* __restrict__ lam,
                                                     float* __restrict__ out,
                                                     float* __restrict__ R1,
                                                     float* __restrict__ R2,
                                                     unsigned* __restrict__ cnt) {
  __shared__ float sg[4][64];
  __shared__ unsigned is_last;
  const int t = threadIdx.x, b = blockIdx.x;
  const int l = t & 63, q = t >> 6;
  const int kj = b * 64 + l;
  float gp = 0.f;
  for (int blk = q * 32; blk < q * 32 + 32; ++blk) gp += P2[(size_t)blk * 4096 + kj];
  sg[q][l] = gp;
  float a = (t < 16) ? P1[b * 16 + t] : 0.f;
  __syncthreads();
  if (q == 0) {
    float g = (sg[0][l] + sg[1][l]) + (sg[2][l] + sg[3][l]);
    float r2 = g * g;
    float r1 = a;
#pragma unroll
    for (int off = 32; off > 0; off >>= 1) {
      r2 += __shfl_down(r2, off, 64);
      r1 += __shfl_down(r1, off, 64);
    }
    if (l == 0) {
      R1[b] = r1;
      R2[b] = r2;
    }
  }
  if (t == 0) {
    __threadfence();  // publish R1[b]/R2[b]
    unsigned old = atomicAdd(cnt, 1u);
    __threadfence();  // acquire for last block's reads
    is_last = (old == 63u) ? 1u : 0u;
  }
  __syncthreads();
  if (is_last && t < 64) {
    float r1 = R1[t], r2 = R2[t];
#pragma unroll
    for (int off = 32; off > 0; off >>= 1) {
      r1 += __shfl_down(r1, off, 64);
      r2 += __shfl_down(r2, off, 64);
    }
    if (t == 0) out[0] = r1 + lam[0] * r2;
  }
}

extern "C" void kernel_launch(void* const* d_in, const int* in_sizes, int n_in,
                              void* d_out, int out_size, void* d_ws, size_t ws_size,
                              hipStream_t stream) {
  const float* Fll = (const float*)d_in[0];
  const float* Ful = (const float*)d_in[1];
  const float* Theta = (const float*)d_in[2];
  const float* lam = (const float*)d_in[3];
  float* out = (float*)d_out;

  char* ws = (char*)d_ws;
  ushort* W0 = (ushort*)ws;                            // 1 MB bf16 F_ll
  float* P1 = (float*)(ws + (1u << 20));               // 4 KB
  float* P2 = (float*)(ws + (1u << 20) + (1u << 16));  // 2 MB
  float* R1 = (float*)(ws + 0x310000u);
  float* R2 = (float*)(ws + 0x310400u);
  unsigned* cnt = (unsigned*)(ws + 0x310800u);

  term2_kernel<<<128, 256, 0, stream>>>(Fll, Ful, P2, W0, cnt);
  term1_kernel<<<1024, 256, 0, stream>>>(Theta, W0, P1);
  stage2_kernel<<<64, 256, 0, stream>>>(P1, P2, lam, out, R1, R2, cnt);
}